// Round 8
// baseline (581.011 us; speedup 1.0000x reference)
//
#include <hip/hip_runtime.h>

// SoftDTW forward, B=64, T=1024, D=8, gamma=1.0, out = mean over batch of R[T,T].
//
// R8 = R6 pipeline, dual-DP blocks. R6 post-mortem: period 1092 cyc/step =
// 665 issue + ~430 exposed chain latency at 1 wave/SIMD; R4 showed 2
// waves/SIMD hides the chain completely (period == issue). So: one 512-thread
// block = TWO independent 4-wave DP pipelines (waves 0-3 -> batch 2blk,
// waves 4-7 -> batch 2blk+1). Wave w lands on SIMD w%4 -> each SIMD hosts
// one wave of each DP: independent streams, full TLP, no cross-DP sync.
// Per-DP everything (tile layout, softmin, sync protocol) is byte-identical
// to R6. Grid 32 blocks; LDS 106 KiB -> 1 block/CU.

typedef float v2f __attribute__((ext_vector_type(2)));

static constexpr int T      = 1024;
static constexpr int NB     = 64;        // batches
static constexpr int NBLK   = 32;        // blocks (2 batches each)
static constexpr int NTH    = 512;       // 8 waves = 2 DPs x 4 waves
static constexpr int NW     = 4;         // waves per DP
static constexpr int CT     = 2;
static constexpr int NQ     = T / CT;    // 512 col-tiles
static constexpr int WSTEPS = NQ + 63;   // 575 per-wave staircase steps

#define BIGF 1e10f
#define L2EF 1.4426950408889634f
#define LN2F 0.6931471805599453f

__device__ __forceinline__ float fexp2(float x) { return __builtin_amdgcn_exp2f(x); }
__device__ __forceinline__ float flog2(float x) { return __builtin_amdgcn_logf(x); }

// softmin in base-2 domain, 3 trans: m - log2(1 + 2^(m-med) + 2^(m-max)).
__device__ __forceinline__ float softmin2(float a, float b, float c) {
  float m = fminf(fminf(a, b), c);
  float M = fmaxf(fmaxf(a, b), c);
  float e = __builtin_amdgcn_fmed3f(a, b, c);
  float s = fexp2(m - e) + fexp2(m - M);
  return m - flog2(1.0f + s);
}

__device__ __forceinline__ v2f pkfma(v2f a, v2f b, v2f c) {
  v2f d;
  asm("v_pk_fma_f32 %0, %1, %2, %3" : "=v"(d) : "v"(a), "v"(b), "v"(c));
  return d;
}

__device__ __forceinline__ v2f lo2(const float4& c) { v2f r; r.x = c.x; r.y = c.y; return r; }
__device__ __forceinline__ v2f hi2(const float4& c) { v2f r; r.x = c.z; r.y = c.w; return r; }

// (dot_col0, dot_col1) for one pred row (dup pairs pp[0..7]) vs interleaved
// tile chunks C[0..3]; seed = (pn+tn0, pn+tn1), everything pre-scaled.
__device__ __forceinline__ v2f dotpk(v2f seed, const v2f* pp, const float4* C) {
  v2f a = seed;
  a = pkfma(pp[0], lo2(C[0]), a);
  a = pkfma(pp[1], hi2(C[0]), a);
  a = pkfma(pp[2], lo2(C[1]), a);
  a = pkfma(pp[3], hi2(C[1]), a);
  a = pkfma(pp[4], lo2(C[2]), a);
  a = pkfma(pp[5], hi2(C[2]), a);
  a = pkfma(pp[6], lo2(C[3]), a);
  a = pkfma(pp[7], hi2(C[3]), a);
  return a;
}

// One staircase step: 4 rows x 2 cols of cells. CUR/NXT: float4[5] reg tiles
// (chunk 4 = scaled norms in .x/.y). Per-DP state; dp/wl select partitions.
#define STEP(SW, CUR, NXT)                                                   \
  {                                                                          \
    const int sw_ = (SW);                                                    \
    float2 cb = make_float2(BIGF, BIGF);                                     \
    if (wl > 0 && sw_ < NQ) {                                                \
      if ((sw_ & 3) == 0) {                                                  \
        const int need = ((sw_ + 3 < NQ) ? sw_ + 3 : NQ - 1) + 63;           \
        while (seen < need) {                                                 \
          seen = __hip_atomic_load(&prog_s[w - 1], __ATOMIC_ACQUIRE,         \
                                   __HIP_MEMORY_SCOPE_WORKGROUP);            \
          if (seen < need) __builtin_amdgcn_s_sleep(1);                      \
        }                                                                    \
      }                                                                      \
      cb = buf_s[dp][(wl - 1) * NQ + sw_]; /* wave-uniform broadcast read */ \
    }                                                                        \
    float na0 = __shfl_up(vD0, 1, 64);                                       \
    float na1 = __shfl_up(vD1, 1, 64);                                       \
    float a0 = (lane == 0) ? cb.x : na0;                                     \
    float a1 = (lane == 0) ? cb.y : na1;                                     \
    const int q = sw_ - lane;                                                \
    { /* prefetch next tile (clamped; junk-safe for idle lanes) */           \
      int qn = sw_ + 1 - lane;                                               \
      qn = qn < 0 ? 0 : (qn > NQ - 1 ? NQ - 1 : qn);                         \
      const float4* bp = &tgt4_s[dp][qn * 5];                                \
      NXT[0] = bp[0]; NXT[1] = bp[1]; NXT[2] = bp[2]; NXT[3] = bp[3];        \
      NXT[4] = bp[4];                                                        \
    }                                                                        \
    if (q >= 0 && q < NQ) {                                                  \
      const float tn0 = CUR[4].x, tn1 = CUR[4].y;                            \
      v2f sA; sA.x = pnA + tn0; sA.y = pnA + tn1;                            \
      v2f sB; sB.x = pnB + tn0; sB.y = pnB + tn1;                            \
      v2f sC; sC.x = pnC + tn0; sC.y = pnC + tn1;                            \
      v2f sD; sD.x = pnD + tn0; sD.y = pnD + tn1;                            \
      v2f accA = dotpk(sA, ppA, CUR);                                        \
      v2f accB = dotpk(sB, ppB, CUR);                                        \
      v2f accC = dotpk(sC, ppC, CUR);                                        \
      v2f accD = dotpk(sD, ppD, CUR);                                        \
      float vA0 = accA.x + softmin2(carry, a0, lA);                          \
      float vA1 = accA.y + softmin2(a0, a1, vA0);                            \
      float vB0 = accB.x + softmin2(lA, vA0, lB);                            \
      float vB1 = accB.y + softmin2(vA0, vA1, vB0);                          \
      float vC0 = accC.x + softmin2(lB, vB0, lC);                            \
      float vC1 = accC.y + softmin2(vB0, vB1, vC0);                          \
      vD0 = accD.x + softmin2(lC, vC0, lD);                                  \
      vD1 = accD.y + softmin2(vC0, vC1, vD0);                                \
      lA = vA1; lB = vB1; lC = vC1; lD = vD1; carry = a1;                    \
      if (lane == 63 && wl < NW - 1)                                         \
        buf_s[dp][wl * NQ + q] = make_float2(vD0, vD1);                      \
      if (wl == NW - 1 && lane == 63 && q == NQ - 1) ws[b] = vD1 * LN2F;     \
    }                                                                        \
    if (lane == 63 && wl < NW - 1 && ((sw_ & 3) == 3 || sw_ == WSTEPS - 1))  \
      __hip_atomic_store(&prog_s[w], sw_, __ATOMIC_RELEASE,                  \
                         __HIP_MEMORY_SCOPE_WORKGROUP);                      \
  }

__global__ __launch_bounds__(NTH) void sdtw_kernel(const float* __restrict__ pred,
                                                   const float* __restrict__ target,
                                                   float* __restrict__ ws) {
  __shared__ float4 tgt4_s[2][NQ * 5];       // 2 x 40 KiB, 80B-stride tiles
  __shared__ float2 buf_s[2][(NW - 1) * NQ]; // 2 x 12 KiB handoff
  __shared__ int prog_s[8];

  const int t    = threadIdx.x;
  const int w    = t >> 6;
  const int lane = t & 63;
  const int dp   = w >> 2;   // which DP pipeline (0/1)
  const int wl   = w & 3;    // wave within DP
  const int td   = t & 255;  // thread within DP
  const int b    = blockIdx.x * 2 + dp;
  const float* pr = pred + (size_t)b * T * 8;
  const float* tg = target + (size_t)b * T * 8;

  // ---- stage target: DP-thread td stages tiles 2td, 2td+1 -----------------
  // tile chunk k = {A[2k], B[2k], A[2k+1], B[2k+1]} * (-2*log2e); chunk 4 =
  // (|A|^2*log2e, |B|^2*log2e, 0, 0). A = row 2q, B = row 2q+1.
  {
    const float4* tg4 = reinterpret_cast<const float4*>(tg);
    const float s = -2.0f * L2EF;
#pragma unroll
    for (int h = 0; h < 2; ++h) { // tile 2td+h
      float4 u0 = tg4[td * 8 + 4 * h + 0]; // A d0-3
      float4 u1 = tg4[td * 8 + 4 * h + 1]; // A d4-7
      float4 u2 = tg4[td * 8 + 4 * h + 2]; // B d0-3
      float4 u3 = tg4[td * 8 + 4 * h + 3]; // B d4-7
      float tA = (u0.x * u0.x + u0.y * u0.y) + (u0.z * u0.z + u0.w * u0.w) +
                 (u1.x * u1.x + u1.y * u1.y) + (u1.z * u1.z + u1.w * u1.w);
      float tB = (u2.x * u2.x + u2.y * u2.y) + (u2.z * u2.z + u2.w * u2.w) +
                 (u3.x * u3.x + u3.y * u3.y) + (u3.z * u3.z + u3.w * u3.w);
      float4* dst = &tgt4_s[dp][(2 * td + h) * 5];
      dst[0] = make_float4(u0.x * s, u2.x * s, u0.y * s, u2.y * s);
      dst[1] = make_float4(u0.z * s, u2.z * s, u0.w * s, u2.w * s);
      dst[2] = make_float4(u1.x * s, u3.x * s, u1.y * s, u3.y * s);
      dst[3] = make_float4(u1.z * s, u3.z * s, u1.w * s, u3.w * s);
      dst[4] = make_float4(tA * L2EF, tB * L2EF, 0.0f, 0.0f);
    }
  }
  if (t < 8) prog_s[t] = -1;

  // ---- pred rows 4td..4td+3 -> duplicated pair registers + scaled norms ---
  const float4* pr4 = reinterpret_cast<const float4*>(pr);
  float4 qA0 = pr4[td * 8 + 0], qA1 = pr4[td * 8 + 1];
  float4 qB0 = pr4[td * 8 + 2], qB1 = pr4[td * 8 + 3];
  float4 qC0 = pr4[td * 8 + 4], qC1 = pr4[td * 8 + 5];
  float4 qD0 = pr4[td * 8 + 6], qD1 = pr4[td * 8 + 7];
#define NRM(a, bq)                                                           \
  (((a.x * a.x + a.y * a.y) + (a.z * a.z + a.w * a.w) +                      \
    (bq.x * bq.x + bq.y * bq.y) + (bq.z * bq.z + bq.w * bq.w)) * L2EF)
  float pnA = NRM(qA0, qA1), pnB = NRM(qB0, qB1);
  float pnC = NRM(qC0, qC1), pnD = NRM(qD0, qD1);
#define DUP(pp, r0, r1)                                                      \
  pp[0].x = r0.x; pp[0].y = r0.x; pp[1].x = r0.y; pp[1].y = r0.y;            \
  pp[2].x = r0.z; pp[2].y = r0.z; pp[3].x = r0.w; pp[3].y = r0.w;            \
  pp[4].x = r1.x; pp[4].y = r1.x; pp[5].x = r1.y; pp[5].y = r1.y;            \
  pp[6].x = r1.z; pp[6].y = r1.z; pp[7].x = r1.w; pp[7].y = r1.w;
  v2f ppA[8], ppB[8], ppC[8], ppD[8];
  DUP(ppA, qA0, qA1) DUP(ppB, qB0, qB1) DUP(ppC, qC0, qC1) DUP(ppD, qD0, qD1)

  __syncthreads(); // staging complete (only block-wide barrier)

  // ---- DP state ------------------------------------------------------------
  float lA = BIGF, lB = BIGF, lC = BIGF, lD = BIGF; // left edges rows 4td..4td+3
  float carry = (td == 0) ? 0.0f : BIGF;            // diag; R[-1][-1]=0
  float vD0 = BIGF, vD1 = BIGF;                     // bottom row (shuffled down)
  int seen = -1;

  float4 tgA[5], tgB[5];
  { // preload tile 0 for sw=0 (all lanes clamp to q=0)
    tgA[0] = tgt4_s[dp][0]; tgA[1] = tgt4_s[dp][1]; tgA[2] = tgt4_s[dp][2];
    tgA[3] = tgt4_s[dp][3]; tgA[4] = tgt4_s[dp][4];
  }

  for (int sw = 0; sw < 576; sw += 2) { // 576 >= WSTEPS; extra step is inert
    STEP(sw, tgA, tgB)
    STEP(sw + 1, tgB, tgA)
  }
}

__global__ void sdtw_reduce(const float* __restrict__ ws, float* __restrict__ out) {
  int l = threadIdx.x; // 64 threads = one wave
  float v = ws[l];
#pragma unroll
  for (int k = 32; k >= 1; k >>= 1) v += __shfl_down(v, k, 64);
  if (l == 0) out[0] = v * (1.0f / (float)NB);
}

extern "C" void kernel_launch(void* const* d_in, const int* in_sizes, int n_in,
                              void* d_out, int out_size, void* d_ws, size_t ws_size,
                              hipStream_t stream) {
  const float* pred   = (const float*)d_in[0];
  const float* target = (const float*)d_in[1];
  float* out = (float*)d_out;
  float* ws  = (float*)d_ws;

  sdtw_kernel<<<NBLK, NTH, 0, stream>>>(pred, target, ws);
  sdtw_reduce<<<1, 64, 0, stream>>>(ws, out);
}